// Round 1
// baseline (356.286 us; speedup 1.0000x reference)
//
#include <hip/hip_runtime.h>

typedef unsigned short u16;
typedef short s16x8 __attribute__((ext_vector_type(8)));
typedef float f32x4 __attribute__((ext_vector_type(4)));

__device__ inline u16 f2bf(float f) {
    unsigned u = __float_as_uint(f);
    u += 0x7FFF + ((u >> 16) & 1);
    return (u16)(u >> 16);
}

__device__ inline f32x4 mfma16(s16x8 a, s16x8 b, f32x4 c) {
    return __builtin_amdgcn_mfma_f32_16x16x32_bf16(a, b, c, 0, 0, 0);
}

// Transpose+convert fp32 [K][N] -> bf16 [N][K]
__global__ void tcvt(const float* __restrict__ in, u16* __restrict__ out, int K, int N) {
    int i = blockIdx.x * 256 + threadIdx.x;
    if (i >= K * N) return;
    int n = i / K, k = i - n * K;
    out[i] = f2bf(in[(size_t)k * N + n]);
}

// LayerNorm over rows of 384 fp32 -> bf16. One wave per row, 4 rows/block.
__global__ __launch_bounds__(256) void ln_kernel(const float* __restrict__ x,
                                                 const float* __restrict__ g,
                                                 const float* __restrict__ be,
                                                 u16* __restrict__ out) {
    int lane = threadIdx.x & 63;
    int w = threadIdx.x >> 6;
    int row = blockIdx.x * 4 + w;
    const float* xr = x + (size_t)row * 384;
    float v[6];
    float s = 0.f, sq = 0.f;
#pragma unroll
    for (int i = 0; i < 6; ++i) {
        v[i] = xr[i * 64 + lane];
        s += v[i];
        sq += v[i] * v[i];
    }
#pragma unroll
    for (int m = 1; m < 64; m <<= 1) {
        s += __shfl_xor(s, m);
        sq += __shfl_xor(sq, m);
    }
    float mu = s * (1.0f / 384.0f);
    float var = sq * (1.0f / 384.0f) - mu * mu;
    float rstd = rsqrtf(var + 1e-5f);
    u16* orow = out + (size_t)row * 384;
#pragma unroll
    for (int i = 0; i < 6; ++i) {
        int col = i * 64 + lane;
        orow[col] = f2bf((v[i] - mu) * rstd * g[col] + be[col]);
    }
}

// bf16 GEMM: A [M][K] row-major, Bt [N][K] row-major (pre-transposed weights).
// Tile 128x128, BK=32, 4 waves each computing 64x64 via 4x4 mfma_16x16x32.
template <int BIAS, int RELU, int RES, int OBF16>
__global__ __launch_bounds__(256) void gemm_kernel(const u16* __restrict__ A,
                                                   const u16* __restrict__ Bt,
                                                   const float* __restrict__ bias,
                                                   const float* __restrict__ res,
                                                   void* __restrict__ out,
                                                   int M, int N, int K) {
    __shared__ u16 La[128 * 40];  // 32 cols + 8 pad (80B row stride, 16B aligned)
    __shared__ u16 Lb[128 * 40];
    int tid = threadIdx.x;
    int lane = tid & 63, w = tid >> 6;
    int wm = w >> 1, wn = w & 1;
    int lr = lane & 15, lg = lane >> 4;
    int m0 = blockIdx.y * 128, n0 = blockIdx.x * 128;

    f32x4 acc[4][4];
    f32x4 zero = {0.f, 0.f, 0.f, 0.f};
#pragma unroll
    for (int mt = 0; mt < 4; ++mt)
#pragma unroll
        for (int nt = 0; nt < 4; ++nt) acc[mt][nt] = zero;

    for (int k0 = 0; k0 < K; k0 += 32) {
        __syncthreads();
#pragma unroll
        for (int i = 0; i < 2; ++i) {
            int c = tid + i * 256;
            int row = c >> 2, cp = c & 3;
            *(int4*)&La[row * 40 + cp * 8] =
                *(const int4*)&A[(size_t)(m0 + row) * K + k0 + cp * 8];
            *(int4*)&Lb[row * 40 + cp * 8] =
                *(const int4*)&Bt[(size_t)(n0 + row) * K + k0 + cp * 8];
        }
        __syncthreads();
        s16x8 af[4], bfr[4];
#pragma unroll
        for (int mt = 0; mt < 4; ++mt)
            af[mt] = *(const s16x8*)&La[(wm * 64 + mt * 16 + lr) * 40 + lg * 8];
#pragma unroll
        for (int nt = 0; nt < 4; ++nt)
            bfr[nt] = *(const s16x8*)&Lb[(wn * 64 + nt * 16 + lr) * 40 + lg * 8];
#pragma unroll
        for (int mt = 0; mt < 4; ++mt)
#pragma unroll
            for (int nt = 0; nt < 4; ++nt)
                acc[mt][nt] = mfma16(af[mt], bfr[nt], acc[mt][nt]);
    }

#pragma unroll
    for (int mt = 0; mt < 4; ++mt) {
#pragma unroll
        for (int nt = 0; nt < 4; ++nt) {
            int m_base = m0 + wm * 64 + mt * 16 + lg * 4;
            int n = n0 + wn * 64 + nt * 16 + lr;
            float bv = BIAS ? bias[n] : 0.0f;
#pragma unroll
            for (int r = 0; r < 4; ++r) {
                size_t idx = (size_t)(m_base + r) * N + n;
                float val = acc[mt][nt][r] + bv;
                if (RES) val += res[idx];
                if (RELU) val = fmaxf(val, 0.0f);
                if (OBF16)
                    ((u16*)out)[idx] = f2bf(val);
                else
                    ((float*)out)[idx] = val;
            }
        }
    }
}

// Causal attention for one (b, h, 128-q-row tile). qkv: [B*T][1152] bf16
// (cols: q 0-383, k 384-767, v 768-1151; within each, h*64+d).
// 8 waves x 16 q-rows. Full 256-col score row per wave in registers.
__global__ __launch_bounds__(512) void attn_kernel(const u16* __restrict__ qkv,
                                                   u16* __restrict__ aout) {
    __shared__ u16 Kl[256 * 72];   // K rows [t][d], pad 64->72
    __shared__ u16 Vt[64 * 264];   // V transposed [d][t], pad 256->264
    __shared__ u16 Pl[8 * 16 * 264];  // per-wave P [16][t], pad
    int qt = blockIdx.x, h = blockIdx.y, b = blockIdx.z;
    int tid = threadIdx.x, lane = tid & 63, w = tid >> 6;
    int lr = lane & 15, lg = lane >> 4;
    const u16* qb = qkv + (size_t)b * 256 * 1152;

#pragma unroll
    for (int i = 0; i < 4; ++i) {
        int c = tid + i * 512;
        int t = c >> 3, dch = c & 7;
        *(int4*)&Kl[t * 72 + dch * 8] =
            *(const int4*)(qb + (size_t)t * 1152 + 384 + h * 64 + dch * 8);
        union { int4 v; u16 u[8]; } vv;
        vv.v = *(const int4*)(qb + (size_t)t * 1152 + 768 + h * 64 + dch * 8);
#pragma unroll
        for (int j = 0; j < 8; ++j) Vt[(dch * 8 + j) * 264 + t] = vv.u[j];
    }

    int q0 = qt * 128;
    const u16* qrow = qb + (size_t)(q0 + w * 16 + lr) * 1152 + h * 64;
    s16x8 qf0 = *(const s16x8*)(qrow + lg * 8);
    s16x8 qf1 = *(const s16x8*)(qrow + 32 + lg * 8);

    __syncthreads();

    f32x4 zero = {0.f, 0.f, 0.f, 0.f};
    f32x4 s[16];
#pragma unroll
    for (int nt = 0; nt < 16; ++nt) s[nt] = zero;
#pragma unroll
    for (int nt = 0; nt < 16; ++nt) {
        s16x8 kf0 = *(const s16x8*)&Kl[(nt * 16 + lr) * 72 + lg * 8];
        s16x8 kf1 = *(const s16x8*)&Kl[(nt * 16 + lr) * 72 + 32 + lg * 8];
        s[nt] = mfma16(qf0, kf0, s[nt]);
        s[nt] = mfma16(qf1, kf1, s[nt]);
    }

    // scale + causal mask + row max (rows: lg*4+r, cols: nt*16+lr)
    int ib = q0 + w * 16 + lg * 4;
    float mx[4] = {-1e30f, -1e30f, -1e30f, -1e30f};
#pragma unroll
    for (int nt = 0; nt < 16; ++nt) {
        int jg = nt * 16 + lr;
#pragma unroll
        for (int r = 0; r < 4; ++r) {
            float val = s[nt][r] * 0.125f;
            val = (jg <= ib + r) ? val : -1e30f;
            s[nt][r] = val;
            mx[r] = fmaxf(mx[r], val);
        }
    }
#pragma unroll
    for (int r = 0; r < 4; ++r) {
        mx[r] = fmaxf(mx[r], __shfl_xor(mx[r], 1));
        mx[r] = fmaxf(mx[r], __shfl_xor(mx[r], 2));
        mx[r] = fmaxf(mx[r], __shfl_xor(mx[r], 4));
        mx[r] = fmaxf(mx[r], __shfl_xor(mx[r], 8));
    }
    float rs[4] = {0.f, 0.f, 0.f, 0.f};
#pragma unroll
    for (int nt = 0; nt < 16; ++nt) {
#pragma unroll
        for (int r = 0; r < 4; ++r) {
            float p = __expf(s[nt][r] - mx[r]);
            s[nt][r] = p;
            rs[r] += p;
        }
    }
#pragma unroll
    for (int r = 0; r < 4; ++r) {
        rs[r] += __shfl_xor(rs[r], 1);
        rs[r] += __shfl_xor(rs[r], 2);
        rs[r] += __shfl_xor(rs[r], 4);
        rs[r] += __shfl_xor(rs[r], 8);
    }
    // write unnormalized P (bf16) to LDS
    u16* Pw = &Pl[w * 16 * 264];
#pragma unroll
    for (int nt = 0; nt < 16; ++nt)
#pragma unroll
        for (int r = 0; r < 4; ++r)
            Pw[(lg * 4 + r) * 264 + nt * 16 + lr] = f2bf(s[nt][r]);

    __syncthreads();

    f32x4 o[4];
#pragma unroll
    for (int nt = 0; nt < 4; ++nt) o[nt] = zero;
#pragma unroll
    for (int kc = 0; kc < 8; ++kc) {
        s16x8 pf = *(const s16x8*)&Pw[lr * 264 + kc * 32 + lg * 8];
#pragma unroll
        for (int nt = 0; nt < 4; ++nt) {
            s16x8 vf = *(const s16x8*)&Vt[(nt * 16 + lr) * 264 + kc * 32 + lg * 8];
            o[nt] = mfma16(pf, vf, o[nt]);
        }
    }
    float inv[4];
#pragma unroll
    for (int r = 0; r < 4; ++r) inv[r] = 1.0f / rs[r];
    u16* ob = aout + (size_t)(b * 256 + q0 + w * 16) * 384 + h * 64;
#pragma unroll
    for (int nt = 0; nt < 4; ++nt)
#pragma unroll
        for (int r = 0; r < 4; ++r)
            ob[(size_t)(lg * 4 + r) * 384 + nt * 16 + lr] = f2bf(o[nt][r] * inv[r]);
}

extern "C" void kernel_launch(void* const* d_in, const int* in_sizes, int n_in,
                              void* d_out, int out_size, void* d_ws, size_t ws_size,
                              hipStream_t stream) {
    const float* x   = (const float*)d_in[0];
    const float* Wk  = (const float*)d_in[1];
    const float* Wq  = (const float*)d_in[2];
    const float* Wv  = (const float*)d_in[3];
    const float* Wo  = (const float*)d_in[4];
    const float* bo  = (const float*)d_in[5];
    const float* W1  = (const float*)d_in[6];
    const float* b1  = (const float*)d_in[7];
    const float* W2  = (const float*)d_in[8];
    const float* b2  = (const float*)d_in[9];
    const float* g1  = (const float*)d_in[10];
    const float* be1 = (const float*)d_in[11];
    const float* g2  = (const float*)d_in[12];
    const float* be2 = (const float*)d_in[13];

    char* ws = (char*)d_ws;
    u16*   hbuf = (u16*)(ws + 0);            // 25165824 B (h1, later h2)
    u16*   qkv  = (u16*)(ws + 25165824);     // 75497472 B
    u16*   ao   = (u16*)(ws + 100663296);    // 25165824 B
    float* x1   = (float*)(ws + 125829120);  // 50331648 B
    u16*   ubuf = (u16*)(ws + 25165824);     // 100663296 B (aliases qkv+ao, both dead)
    u16*   wT   = (u16*)(ws + 176160768);    // 3538944 B of bf16 weights
    u16* wqkvT = wT;                  // [1152][384]: q rows 0-383, k 384-767, v 768-1151
    u16* woT   = wT + 442368;         // [384][384]
    u16* w1T   = woT + 147456;        // [1536][384]
    u16* w2T   = w1T + 589824;        // [384][1536]

    tcvt<<<576, 256, 0, stream>>>(Wq, wqkvT, 384, 384);
    tcvt<<<576, 256, 0, stream>>>(Wk, wqkvT + 147456, 384, 384);
    tcvt<<<576, 256, 0, stream>>>(Wv, wqkvT + 294912, 384, 384);
    tcvt<<<576, 256, 0, stream>>>(Wo, woT, 384, 384);
    tcvt<<<2304, 256, 0, stream>>>(W1, w1T, 384, 1536);
    tcvt<<<2304, 256, 0, stream>>>(W2, w2T, 1536, 384);

    // h1 = LN(x)
    ln_kernel<<<8192, 256, 0, stream>>>(x, g1, be1, hbuf);
    // qkv = h1 @ [Wq|Wk|Wv]
    gemm_kernel<0, 0, 0, 1><<<dim3(9, 256), 256, 0, stream>>>(
        hbuf, wqkvT, nullptr, nullptr, qkv, 32768, 1152, 384);
    // attention
    attn_kernel<<<dim3(2, 6, 128), 512, 0, stream>>>(qkv, ao);
    // x1 = x + ao @ Wo + bo
    gemm_kernel<1, 0, 1, 0><<<dim3(3, 256), 256, 0, stream>>>(
        ao, woT, bo, x, x1, 32768, 384, 384);
    // h2 = LN(x1)
    ln_kernel<<<8192, 256, 0, stream>>>(x1, g2, be2, hbuf);
    // u = relu(h2 @ W1 + b1)
    gemm_kernel<1, 1, 0, 1><<<dim3(12, 256), 256, 0, stream>>>(
        hbuf, w1T, b1, nullptr, ubuf, 32768, 1536, 384);
    // out = x1 + u @ W2 + b2
    gemm_kernel<1, 0, 1, 0><<<dim3(3, 256), 256, 0, stream>>>(
        ubuf, w2T, b2, x1, (float*)d_out, 32768, 384, 1536);
}

// Round 2
// 330.612 us; speedup vs baseline: 1.0777x; 1.0777x over previous
//
#include <hip/hip_runtime.h>

typedef unsigned short u16;
typedef short s16x8 __attribute__((ext_vector_type(8)));
typedef float f32x4 __attribute__((ext_vector_type(4)));

__device__ inline u16 f2bf(float f) {
    unsigned u = __float_as_uint(f);
    u += 0x7FFF + ((u >> 16) & 1);
    return (u16)(u >> 16);
}

__device__ inline f32x4 mfma16(s16x8 a, s16x8 b, f32x4 c) {
    return __builtin_amdgcn_mfma_f32_16x16x32_bf16(a, b, c, 0, 0, 0);
}

// async global->LDS, 16B per lane. LDS dest is wave-uniform base + lane*16.
__device__ __forceinline__ void gl16(const u16* g, u16* l) {
    __builtin_amdgcn_global_load_lds(
        (const __attribute__((address_space(1))) void*)g,
        (__attribute__((address_space(3))) void*)l, 16, 0, 0);
}

// Transpose+convert fp32 [K][N] -> bf16 [N][K]
__global__ void tcvt(const float* __restrict__ in, u16* __restrict__ out, int K, int N) {
    int i = blockIdx.x * 256 + threadIdx.x;
    if (i >= K * N) return;
    int n = i / K, k = i - n * K;
    out[i] = f2bf(in[(size_t)k * N + n]);
}

// LayerNorm over rows of 384 fp32 -> bf16. One wave per row, 4 rows/block.
__global__ __launch_bounds__(256) void ln_kernel(const float* __restrict__ x,
                                                 const float* __restrict__ g,
                                                 const float* __restrict__ be,
                                                 u16* __restrict__ out) {
    int lane = threadIdx.x & 63;
    int w = threadIdx.x >> 6;
    int row = blockIdx.x * 4 + w;
    const float* xr = x + (size_t)row * 384;
    float v[6];
    float s = 0.f, sq = 0.f;
#pragma unroll
    for (int i = 0; i < 6; ++i) {
        v[i] = xr[i * 64 + lane];
        s += v[i];
        sq += v[i] * v[i];
    }
#pragma unroll
    for (int m = 1; m < 64; m <<= 1) {
        s += __shfl_xor(s, m);
        sq += __shfl_xor(sq, m);
    }
    float mu = s * (1.0f / 384.0f);
    float var = sq * (1.0f / 384.0f) - mu * mu;
    float rstd = rsqrtf(var + 1e-5f);
    u16* orow = out + (size_t)row * 384;
#pragma unroll
    for (int i = 0; i < 6; ++i) {
        int col = i * 64 + lane;
        orow[col] = f2bf((v[i] - mu) * rstd * g[col] + be[col]);
    }
}

// bf16 GEMM (m97 structure): A [M][K] rm, Bt [N][K] rm. Tile 128x128, BK=64,
// 4 waves x (64x64). global_load_lds width16, linear LDS + XOR slot swizzle
// (swizzled SOURCE addr + swizzled READ addr; LDS write is linear).
template <int BIAS, int RELU, int RES, int OBF16>
__global__ __launch_bounds__(256) void gemm_kernel(const u16* __restrict__ A,
                                                   const u16* __restrict__ Bt,
                                                   const float* __restrict__ bias,
                                                   const float* __restrict__ res,
                                                   void* __restrict__ out,
                                                   int M, int N, int K) {
    __shared__ u16 La[128 * 64];
    __shared__ u16 Lb[128 * 64];
    int tid = threadIdx.x;
    int lane = tid & 63, w = tid >> 6;
    int wm = w >> 1, wn = w & 1;
    int lr = lane & 15, lg = lane >> 4;
    int m0 = blockIdx.y * 128, n0 = blockIdx.x * 128;

    // staging geometry: inst i of wave w covers rows w*32+i*8 .. +8, 8 lanes/row.
    // lane's row-within-8 = lane>>3; global col slot = (lane&7) ^ (lane>>3).
    int rsub = lane >> 3;
    int colx = ((lane & 7) ^ rsub) * 8;
    const u16* pa[4];
    const u16* pb[4];
    u16* la[4];
    u16* lb[4];
#pragma unroll
    for (int i = 0; i < 4; ++i) {
        int rr = w * 32 + i * 8 + rsub;
        pa[i] = A + (size_t)(m0 + rr) * K + colx;
        pb[i] = Bt + (size_t)(n0 + rr) * K + colx;
        la[i] = &La[(w * 4 + i) * 512];
        lb[i] = &Lb[(w * 4 + i) * 512];
    }

    f32x4 acc[4][4];
    f32x4 zero = {0.f, 0.f, 0.f, 0.f};
#pragma unroll
    for (int mt = 0; mt < 4; ++mt)
#pragma unroll
        for (int nt = 0; nt < 4; ++nt) acc[mt][nt] = zero;

    for (int k0 = 0; k0 < K; k0 += 64) {
        __syncthreads();
#pragma unroll
        for (int i = 0; i < 4; ++i) {
            gl16(pa[i] + k0, la[i]);
            gl16(pb[i] + k0, lb[i]);
        }
        __syncthreads();  // drains vmcnt -> LDS tiles ready
        s16x8 af[2][4], bfr[2][4];
#pragma unroll
        for (int kk = 0; kk < 2; ++kk) {
#pragma unroll
            for (int t = 0; t < 4; ++t) {
                int mr = wm * 64 + t * 16 + lr;
                int nr = wn * 64 + t * 16 + lr;
                int sl = ((kk * 4 + lg) ^ (lr & 7)) * 8;
                af[kk][t] = *(const s16x8*)&La[mr * 64 + sl];
                bfr[kk][t] = *(const s16x8*)&Lb[nr * 64 + sl];
            }
        }
#pragma unroll
        for (int kk = 0; kk < 2; ++kk)
#pragma unroll
            for (int mt = 0; mt < 4; ++mt)
#pragma unroll
                for (int nt = 0; nt < 4; ++nt)
                    acc[mt][nt] = mfma16(af[kk][mt], bfr[kk][nt], acc[mt][nt]);
    }

#pragma unroll
    for (int mt = 0; mt < 4; ++mt) {
#pragma unroll
        for (int nt = 0; nt < 4; ++nt) {
            int m_base = m0 + wm * 64 + mt * 16 + lg * 4;
            int n = n0 + wn * 64 + nt * 16 + lr;
            float bv = BIAS ? bias[n] : 0.0f;
#pragma unroll
            for (int r = 0; r < 4; ++r) {
                size_t idx = (size_t)(m_base + r) * N + n;
                float val = acc[mt][nt][r] + bv;
                if (RES) val += res[idx];
                if (RELU) val = fmaxf(val, 0.0f);
                if (OBF16)
                    ((u16*)out)[idx] = f2bf(val);
                else
                    ((float*)out)[idx] = val;
            }
        }
    }
}

// Causal attention for one (b, h, 128-q-row tile). qkv: [B*T][1152] bf16
// (cols: q 0-383, k 384-767, v 768-1151; within each, h*64+d).
// 8 waves x 16 q-rows. Full 256-col score row per wave in registers.
__global__ __launch_bounds__(512) void attn_kernel(const u16* __restrict__ qkv,
                                                   u16* __restrict__ aout) {
    __shared__ u16 Kl[256 * 72];   // K rows [t][d], pad 64->72
    __shared__ u16 Vt[64 * 264];   // V transposed [d][t], pad 256->264
    __shared__ u16 Pl[8 * 16 * 264];  // per-wave P [16][t], pad
    int qt = blockIdx.x, h = blockIdx.y, b = blockIdx.z;
    int tid = threadIdx.x, lane = tid & 63, w = tid >> 6;
    int lr = lane & 15, lg = lane >> 4;
    const u16* qb = qkv + (size_t)b * 256 * 1152;

#pragma unroll
    for (int i = 0; i < 4; ++i) {
        int c = tid + i * 512;
        int t = c >> 3, dch = c & 7;
        *(int4*)&Kl[t * 72 + dch * 8] =
            *(const int4*)(qb + (size_t)t * 1152 + 384 + h * 64 + dch * 8);
        union { int4 v; u16 u[8]; } vv;
        vv.v = *(const int4*)(qb + (size_t)t * 1152 + 768 + h * 64 + dch * 8);
#pragma unroll
        for (int j = 0; j < 8; ++j) Vt[(dch * 8 + j) * 264 + t] = vv.u[j];
    }

    int q0 = qt * 128;
    const u16* qrow = qb + (size_t)(q0 + w * 16 + lr) * 1152 + h * 64;
    s16x8 qf0 = *(const s16x8*)(qrow + lg * 8);
    s16x8 qf1 = *(const s16x8*)(qrow + 32 + lg * 8);

    __syncthreads();

    f32x4 zero = {0.f, 0.f, 0.f, 0.f};
    f32x4 s[16];
#pragma unroll
    for (int nt = 0; nt < 16; ++nt) s[nt] = zero;
#pragma unroll
    for (int nt = 0; nt < 16; ++nt) {
        s16x8 kf0 = *(const s16x8*)&Kl[(nt * 16 + lr) * 72 + lg * 8];
        s16x8 kf1 = *(const s16x8*)&Kl[(nt * 16 + lr) * 72 + 32 + lg * 8];
        s[nt] = mfma16(qf0, kf0, s[nt]);
        s[nt] = mfma16(qf1, kf1, s[nt]);
    }

    // scale + causal mask + row max (rows: lg*4+r, cols: nt*16+lr)
    int ib = q0 + w * 16 + lg * 4;
    float mx[4] = {-1e30f, -1e30f, -1e30f, -1e30f};
#pragma unroll
    for (int nt = 0; nt < 16; ++nt) {
        int jg = nt * 16 + lr;
#pragma unroll
        for (int r = 0; r < 4; ++r) {
            float val = s[nt][r] * 0.125f;
            val = (jg <= ib + r) ? val : -1e30f;
            s[nt][r] = val;
            mx[r] = fmaxf(mx[r], val);
        }
    }
#pragma unroll
    for (int r = 0; r < 4; ++r) {
        mx[r] = fmaxf(mx[r], __shfl_xor(mx[r], 1));
        mx[r] = fmaxf(mx[r], __shfl_xor(mx[r], 2));
        mx[r] = fmaxf(mx[r], __shfl_xor(mx[r], 4));
        mx[r] = fmaxf(mx[r], __shfl_xor(mx[r], 8));
    }
    float rs[4] = {0.f, 0.f, 0.f, 0.f};
#pragma unroll
    for (int nt = 0; nt < 16; ++nt) {
#pragma unroll
        for (int r = 0; r < 4; ++r) {
            float p = __expf(s[nt][r] - mx[r]);
            s[nt][r] = p;
            rs[r] += p;
        }
    }
#pragma unroll
    for (int r = 0; r < 4; ++r) {
        rs[r] += __shfl_xor(rs[r], 1);
        rs[r] += __shfl_xor(rs[r], 2);
        rs[r] += __shfl_xor(rs[r], 4);
        rs[r] += __shfl_xor(rs[r], 8);
    }
    // write unnormalized P (bf16) to LDS
    u16* Pw = &Pl[w * 16 * 264];
#pragma unroll
    for (int nt = 0; nt < 16; ++nt)
#pragma unroll
        for (int r = 0; r < 4; ++r)
            Pw[(lg * 4 + r) * 264 + nt * 16 + lr] = f2bf(s[nt][r]);

    __syncthreads();

    f32x4 o[4];
#pragma unroll
    for (int nt = 0; nt < 4; ++nt) o[nt] = zero;
#pragma unroll
    for (int kc = 0; kc < 8; ++kc) {
        s16x8 pf = *(const s16x8*)&Pw[lr * 264 + kc * 32 + lg * 8];
#pragma unroll
        for (int nt = 0; nt < 4; ++nt) {
            s16x8 vf = *(const s16x8*)&Vt[(nt * 16 + lr) * 264 + kc * 32 + lg * 8];
            o[nt] = mfma16(pf, vf, o[nt]);
        }
    }
    float inv[4];
#pragma unroll
    for (int r = 0; r < 4; ++r) inv[r] = 1.0f / rs[r];
    u16* ob = aout + (size_t)(b * 256 + q0 + w * 16) * 384 + h * 64;
#pragma unroll
    for (int nt = 0; nt < 4; ++nt)
#pragma unroll
        for (int r = 0; r < 4; ++r)
            ob[(size_t)(lg * 4 + r) * 384 + nt * 16 + lr] = f2bf(o[nt][r] * inv[r]);
}

extern "C" void kernel_launch(void* const* d_in, const int* in_sizes, int n_in,
                              void* d_out, int out_size, void* d_ws, size_t ws_size,
                              hipStream_t stream) {
    const float* x   = (const float*)d_in[0];
    const float* Wk  = (const float*)d_in[1];
    const float* Wq  = (const float*)d_in[2];
    const float* Wv  = (const float*)d_in[3];
    const float* Wo  = (const float*)d_in[4];
    const float* bo  = (const float*)d_in[5];
    const float* W1  = (const float*)d_in[6];
    const float* b1  = (const float*)d_in[7];
    const float* W2  = (const float*)d_in[8];
    const float* b2  = (const float*)d_in[9];
    const float* g1  = (const float*)d_in[10];
    const float* be1 = (const float*)d_in[11];
    const float* g2  = (const float*)d_in[12];
    const float* be2 = (const float*)d_in[13];

    char* ws = (char*)d_ws;
    u16*   hbuf = (u16*)(ws + 0);            // 25165824 B (h1, later h2)
    u16*   qkv  = (u16*)(ws + 25165824);     // 75497472 B
    u16*   ao   = (u16*)(ws + 100663296);    // 25165824 B
    float* x1   = (float*)(ws + 125829120);  // 50331648 B
    u16*   ubuf = (u16*)(ws + 25165824);     // 100663296 B (aliases qkv+ao, both dead)
    u16*   wT   = (u16*)(ws + 176160768);    // 3538944 B of bf16 weights
    u16* wqkvT = wT;                  // [1152][384]: q rows 0-383, k 384-767, v 768-1151
    u16* woT   = wT + 442368;         // [384][384]
    u16* w1T   = woT + 147456;        // [1536][384]
    u16* w2T   = w1T + 589824;        // [384][1536]

    tcvt<<<576, 256, 0, stream>>>(Wq, wqkvT, 384, 384);
    tcvt<<<576, 256, 0, stream>>>(Wk, wqkvT + 147456, 384, 384);
    tcvt<<<576, 256, 0, stream>>>(Wv, wqkvT + 294912, 384, 384);
    tcvt<<<576, 256, 0, stream>>>(Wo, woT, 384, 384);
    tcvt<<<2304, 256, 0, stream>>>(W1, w1T, 384, 1536);
    tcvt<<<2304, 256, 0, stream>>>(W2, w2T, 1536, 384);

    // h1 = LN(x)
    ln_kernel<<<8192, 256, 0, stream>>>(x, g1, be1, hbuf);
    // qkv = h1 @ [Wq|Wk|Wv]
    gemm_kernel<0, 0, 0, 1><<<dim3(9, 256), 256, 0, stream>>>(
        hbuf, wqkvT, nullptr, nullptr, qkv, 32768, 1152, 384);
    // attention
    attn_kernel<<<dim3(2, 6, 128), 512, 0, stream>>>(qkv, ao);
    // x1 = x + ao @ Wo + bo
    gemm_kernel<1, 0, 1, 0><<<dim3(3, 256), 256, 0, stream>>>(
        ao, woT, bo, x, x1, 32768, 384, 384);
    // h2 = LN(x1)
    ln_kernel<<<8192, 256, 0, stream>>>(x1, g2, be2, hbuf);
    // u = relu(h2 @ W1 + b1)
    gemm_kernel<1, 1, 0, 1><<<dim3(12, 256), 256, 0, stream>>>(
        hbuf, w1T, b1, nullptr, ubuf, 32768, 1536, 384);
    // out = x1 + u @ W2 + b2
    gemm_kernel<1, 0, 1, 0><<<dim3(3, 256), 256, 0, stream>>>(
        ubuf, w2T, b2, x1, (float*)d_out, 32768, 384, 1536);
}

// Round 3
// 288.526 us; speedup vs baseline: 1.2349x; 1.1459x over previous
//
#include <hip/hip_runtime.h>

typedef unsigned short u16;
typedef short s16x8 __attribute__((ext_vector_type(8)));
typedef float f32x4 __attribute__((ext_vector_type(4)));

__device__ inline u16 f2bf(float f) {
    unsigned u = __float_as_uint(f);
    u += 0x7FFF + ((u >> 16) & 1);
    return (u16)(u >> 16);
}
__device__ inline float bf2f(u16 h) {
    return __uint_as_float((unsigned)h << 16);
}

__device__ inline f32x4 mfma16(s16x8 a, s16x8 b, f32x4 c) {
    return __builtin_amdgcn_mfma_f32_16x16x32_bf16(a, b, c, 0, 0, 0);
}

// async global->LDS, 16B per lane. LDS dest is wave-uniform base + lane*16.
__device__ __forceinline__ void gl16(const u16* g, u16* l) {
    __builtin_amdgcn_global_load_lds(
        (const __attribute__((address_space(1))) void*)g,
        (__attribute__((address_space(3))) void*)l, 16, 0, 0);
}

// All weight transposes fused in one launch. out = wT layout (bf16):
// [0,147456) Wq^T, [147456,294912) Wk^T, [294912,442368) Wv^T,
// [442368,589824) Wo^T, [589824,1179648) W1^T, [1179648,1769472) W2^T.
__global__ void tcvt_all(const float* __restrict__ Wq, const float* __restrict__ Wk,
                         const float* __restrict__ Wv, const float* __restrict__ Wo,
                         const float* __restrict__ W1, const float* __restrict__ W2,
                         u16* __restrict__ out) {
    int i = blockIdx.x * 256 + threadIdx.x;
    float val;
    if (i < 589824) {
        int q = i / 147456, j = i - q * 147456;
        const float* s = q == 0 ? Wq : q == 1 ? Wk : q == 2 ? Wv : Wo;
        int n = j / 384, k = j - n * 384;
        val = s[k * 384 + n];
    } else if (i < 1179648) {
        int j = i - 589824;
        int n = j / 384, k = j - n * 384;
        val = W1[(size_t)k * 1536 + n];
    } else {
        int j = i - 1179648;
        int n = j / 1536, k = j - n * 1536;
        val = W2[(size_t)k * 384 + n];
    }
    out[i] = f2bf(val);
}

// LayerNorm over rows of 384 fp32 -> bf16. One wave per row, 4 rows/block.
__global__ __launch_bounds__(256) void ln_kernel(const float* __restrict__ x,
                                                 const float* __restrict__ g,
                                                 const float* __restrict__ be,
                                                 u16* __restrict__ out) {
    int lane = threadIdx.x & 63;
    int w = threadIdx.x >> 6;
    int row = blockIdx.x * 4 + w;
    const float* xr = x + (size_t)row * 384;
    float v[6];
    float s = 0.f, sq = 0.f;
#pragma unroll
    for (int i = 0; i < 6; ++i) {
        v[i] = xr[i * 64 + lane];
        s += v[i];
        sq += v[i] * v[i];
    }
#pragma unroll
    for (int m = 1; m < 64; m <<= 1) {
        s += __shfl_xor(s, m);
        sq += __shfl_xor(sq, m);
    }
    float mu = s * (1.0f / 384.0f);
    float var = sq * (1.0f / 384.0f) - mu * mu;
    float rstd = rsqrtf(var + 1e-5f);
    u16* orow = out + (size_t)row * 384;
#pragma unroll
    for (int i = 0; i < 6; ++i) {
        int col = i * 64 + lane;
        orow[col] = f2bf((v[i] - mu) * rstd * g[col] + be[col]);
    }
}

// LayerNorm, bf16 input rows of 384 -> bf16. One wave/row, 48 active lanes x8.
__global__ __launch_bounds__(256) void ln_bf16_kernel(const u16* __restrict__ x,
                                                      const float* __restrict__ g,
                                                      const float* __restrict__ be,
                                                      u16* __restrict__ out) {
    int lane = threadIdx.x & 63;
    int w = threadIdx.x >> 6;
    int row = blockIdx.x * 4 + w;
    const u16* xr = x + (size_t)row * 384;
    bool act = lane < 48;
    float v[8];
    float s = 0.f, sq = 0.f;
    if (act) {
        s16x8 t = *(const s16x8*)&xr[lane * 8];
#pragma unroll
        for (int j = 0; j < 8; ++j) {
            v[j] = bf2f((u16)t[j]);
            s += v[j];
            sq += v[j] * v[j];
        }
    }
#pragma unroll
    for (int m = 1; m < 64; m <<= 1) {
        s += __shfl_xor(s, m);
        sq += __shfl_xor(sq, m);
    }
    float mu = s * (1.0f / 384.0f);
    float var = sq * (1.0f / 384.0f) - mu * mu;
    float rstd = rsqrtf(var + 1e-5f);
    if (act) {
        float4 g0 = *(const float4*)&g[lane * 8];
        float4 g1 = *(const float4*)&g[lane * 8 + 4];
        float4 b0 = *(const float4*)&be[lane * 8];
        float4 b1 = *(const float4*)&be[lane * 8 + 4];
        float gg[8] = {g0.x, g0.y, g0.z, g0.w, g1.x, g1.y, g1.z, g1.w};
        float bb[8] = {b0.x, b0.y, b0.z, b0.w, b1.x, b1.y, b1.z, b1.w};
        u16* orow = out + (size_t)row * 384 + lane * 8;
#pragma unroll
        for (int j = 0; j < 8; ++j)
            orow[j] = f2bf((v[j] - mu) * rstd * gg[j] + bb[j]);
    }
}

// bf16 GEMM, 2-phase double-buffered pipeline. A [M][K] rm, Bt [N][K] rm.
// Tile 128x128, BK=32, 4 waves x (64x64). global_load_lds width16, linear LDS
// write + XOR granule swizzle (pre-swizzled source addr, swizzled read addr).
// Per step: vmcnt(0); s_barrier; issue next-tile gl16; ds_read+MFMA current.
template <int BIAS, int RELU, int RES, int RESBF, int OBF16, int NBX>
__global__ __launch_bounds__(256) void gemm_kernel(const u16* __restrict__ A,
                                                   const u16* __restrict__ Bt,
                                                   const float* __restrict__ bias,
                                                   const void* __restrict__ res,
                                                   void* __restrict__ out,
                                                   int M, int N, int K) {
    __shared__ u16 La[2][128 * 32];
    __shared__ u16 Lb[2][128 * 32];
    int tid = threadIdx.x;
    int lane = tid & 63, w = tid >> 6;
    int wm = w >> 1, wn = w & 1;
    int lr = lane & 15, lg = lane >> 4;

    // bijective XCD chunk swizzle (m204); consecutive wg share A-panels.
    int nwg = gridDim.x;
    int q = nwg >> 3, r = nwg & 7;
    int xcd = blockIdx.x & 7, lin = blockIdx.x >> 3;
    int wg = (xcd < r ? xcd * (q + 1) : r * (q + 1) + (xcd - r) * q) + lin;
    int bx = wg % NBX, by = wg / NBX;
    int m0 = by * 128, n0 = bx * 128;

    // staging: 4 lanes/row (16B each), rows w*32 + i*16 + (lane>>2).
    // reader expects physical granule p at row rr to hold global granule
    // p ^ ((rr>>1)&3); writer lane l sits at physical slot l&3.
    int gslot = ((lane & 3) ^ ((lane >> 3) & 3)) * 8;  // global col offset (elems)
    const u16* pa[2];
    const u16* pb[2];
#pragma unroll
    for (int i = 0; i < 2; ++i) {
        int rr = w * 32 + i * 16 + (lane >> 2);
        pa[i] = A + (size_t)(m0 + rr) * K + gslot;
        pb[i] = Bt + (size_t)(n0 + rr) * K + gslot;
    }

    f32x4 acc[4][4];
    f32x4 zero = {0.f, 0.f, 0.f, 0.f};
#pragma unroll
    for (int mt = 0; mt < 4; ++mt)
#pragma unroll
        for (int nt = 0; nt < 4; ++nt) acc[mt][nt] = zero;

    int sel = (lg ^ ((lr >> 1) & 3)) << 3;  // read-side swizzled granule (elems)
    int nt_steps = K >> 5;

    // prologue: stage tile 0 into buffer 0
    {
        u16* la = La[0] + w * 32 * 32;
        u16* lb = Lb[0] + w * 32 * 32;
        gl16(pa[0], la);
        gl16(pa[1], la + 16 * 32);
        gl16(pb[0], lb);
        gl16(pb[1], lb + 16 * 32);
    }

    for (int t = 0; t < nt_steps; ++t) {
        asm volatile("s_waitcnt vmcnt(0)" ::: "memory");
        __builtin_amdgcn_s_barrier();
        asm volatile("" ::: "memory");
        if (t + 1 < nt_steps) {
            int kc = (t + 1) << 5;
            u16* la = La[(t + 1) & 1] + w * 32 * 32;
            u16* lb = Lb[(t + 1) & 1] + w * 32 * 32;
            gl16(pa[0] + kc, la);
            gl16(pa[1] + kc, la + 16 * 32);
            gl16(pb[0] + kc, lb);
            gl16(pb[1] + kc, lb + 16 * 32);
        }
        const u16* lab = La[t & 1];
        const u16* lbb = Lb[t & 1];
        s16x8 af[4], bfr[4];
#pragma unroll
        for (int tt = 0; tt < 4; ++tt) {
            int mr = wm * 64 + tt * 16 + lr;
            int nr = wn * 64 + tt * 16 + lr;
            af[tt] = *(const s16x8*)&lab[mr * 32 + sel];
            bfr[tt] = *(const s16x8*)&lbb[nr * 32 + sel];
        }
#pragma unroll
        for (int mt = 0; mt < 4; ++mt)
#pragma unroll
            for (int nt = 0; nt < 4; ++nt)
                acc[mt][nt] = mfma16(af[mt], bfr[nt], acc[mt][nt]);
    }

#pragma unroll
    for (int mt = 0; mt < 4; ++mt) {
#pragma unroll
        for (int nt = 0; nt < 4; ++nt) {
            int m_base = m0 + wm * 64 + mt * 16 + lg * 4;
            int n = n0 + wn * 64 + nt * 16 + lr;
            float bv = BIAS ? bias[n] : 0.0f;
#pragma unroll
            for (int r2 = 0; r2 < 4; ++r2) {
                size_t idx = (size_t)(m_base + r2) * N + n;
                float val = acc[mt][nt][r2] + bv;
                if (RES) {
                    if (RESBF)
                        val += bf2f(((const u16*)res)[idx]);
                    else
                        val += ((const float*)res)[idx];
                }
                if (RELU) val = fmaxf(val, 0.0f);
                if (OBF16)
                    ((u16*)out)[idx] = f2bf(val);
                else
                    ((float*)out)[idx] = val;
            }
        }
    }
}

// Causal attention for one (b, h, 128-q-row tile). qkv: [B*T][1152] bf16
// (cols: q 0-383, k 384-767, v 768-1151; within each, h*64+d).
// 8 waves x 16 q-rows. Full 256-col score row per wave in registers.
__global__ __launch_bounds__(512) void attn_kernel(const u16* __restrict__ qkv,
                                                   u16* __restrict__ aout) {
    __shared__ u16 Kl[256 * 72];   // K rows [t][d], pad 64->72
    __shared__ u16 Vt[64 * 264];   // V transposed [d][t], pad 256->264
    __shared__ u16 Pl[8 * 16 * 264];  // per-wave P [16][t], pad
    int qt = blockIdx.x, h = blockIdx.y, b = blockIdx.z;
    int tid = threadIdx.x, lane = tid & 63, w = tid >> 6;
    int lr = lane & 15, lg = lane >> 4;
    const u16* qb = qkv + (size_t)b * 256 * 1152;

#pragma unroll
    for (int i = 0; i < 4; ++i) {
        int c = tid + i * 512;
        int t = c >> 3, dch = c & 7;
        *(int4*)&Kl[t * 72 + dch * 8] =
            *(const int4*)(qb + (size_t)t * 1152 + 384 + h * 64 + dch * 8);
        union { int4 v; u16 u[8]; } vv;
        vv.v = *(const int4*)(qb + (size_t)t * 1152 + 768 + h * 64 + dch * 8);
#pragma unroll
        for (int j = 0; j < 8; ++j) Vt[(dch * 8 + j) * 264 + t] = vv.u[j];
    }

    int q0 = qt * 128;
    const u16* qrow = qb + (size_t)(q0 + w * 16 + lr) * 1152 + h * 64;
    s16x8 qf0 = *(const s16x8*)(qrow + lg * 8);
    s16x8 qf1 = *(const s16x8*)(qrow + 32 + lg * 8);

    __syncthreads();

    f32x4 zero = {0.f, 0.f, 0.f, 0.f};
    f32x4 s[16];
#pragma unroll
    for (int nt = 0; nt < 16; ++nt) s[nt] = zero;
#pragma unroll
    for (int nt = 0; nt < 16; ++nt) {
        s16x8 kf0 = *(const s16x8*)&Kl[(nt * 16 + lr) * 72 + lg * 8];
        s16x8 kf1 = *(const s16x8*)&Kl[(nt * 16 + lr) * 72 + 32 + lg * 8];
        s[nt] = mfma16(qf0, kf0, s[nt]);
        s[nt] = mfma16(qf1, kf1, s[nt]);
    }

    // scale + causal mask + row max (rows: lg*4+r, cols: nt*16+lr)
    int ib = q0 + w * 16 + lg * 4;
    float mx[4] = {-1e30f, -1e30f, -1e30f, -1e30f};
#pragma unroll
    for (int nt = 0; nt < 16; ++nt) {
        int jg = nt * 16 + lr;
#pragma unroll
        for (int r = 0; r < 4; ++r) {
            float val = s[nt][r] * 0.125f;
            val = (jg <= ib + r) ? val : -1e30f;
            s[nt][r] = val;
            mx[r] = fmaxf(mx[r], val);
        }
    }
#pragma unroll
    for (int r = 0; r < 4; ++r) {
        mx[r] = fmaxf(mx[r], __shfl_xor(mx[r], 1));
        mx[r] = fmaxf(mx[r], __shfl_xor(mx[r], 2));
        mx[r] = fmaxf(mx[r], __shfl_xor(mx[r], 4));
        mx[r] = fmaxf(mx[r], __shfl_xor(mx[r], 8));
    }
    float rs[4] = {0.f, 0.f, 0.f, 0.f};
#pragma unroll
    for (int nt = 0; nt < 16; ++nt) {
#pragma unroll
        for (int r = 0; r < 4; ++r) {
            float p = __expf(s[nt][r] - mx[r]);
            s[nt][r] = p;
            rs[r] += p;
        }
    }
#pragma unroll
    for (int r = 0; r < 4; ++r) {
        rs[r] += __shfl_xor(rs[r], 1);
        rs[r] += __shfl_xor(rs[r], 2);
        rs[r] += __shfl_xor(rs[r], 4);
        rs[r] += __shfl_xor(rs[r], 8);
    }
    // write unnormalized P (bf16) to LDS
    u16* Pw = &Pl[w * 16 * 264];
#pragma unroll
    for (int nt = 0; nt < 16; ++nt)
#pragma unroll
        for (int r = 0; r < 4; ++r)
            Pw[(lg * 4 + r) * 264 + nt * 16 + lr] = f2bf(s[nt][r]);

    __syncthreads();

    f32x4 o[4];
#pragma unroll
    for (int nt = 0; nt < 4; ++nt) o[nt] = zero;
#pragma unroll
    for (int kc = 0; kc < 8; ++kc) {
        s16x8 pf = *(const s16x8*)&Pw[lr * 264 + kc * 32 + lg * 8];
#pragma unroll
        for (int nt = 0; nt < 4; ++nt) {
            s16x8 vf = *(const s16x8*)&Vt[(nt * 16 + lr) * 264 + kc * 32 + lg * 8];
            o[nt] = mfma16(pf, vf, o[nt]);
        }
    }
    float inv[4];
#pragma unroll
    for (int r = 0; r < 4; ++r) inv[r] = 1.0f / rs[r];
    u16* ob = aout + (size_t)(b * 256 + q0 + w * 16) * 384 + h * 64;
#pragma unroll
    for (int nt = 0; nt < 4; ++nt)
#pragma unroll
        for (int r = 0; r < 4; ++r)
            ob[(size_t)(lg * 4 + r) * 384 + nt * 16 + lr] = f2bf(o[nt][r] * inv[r]);
}

extern "C" void kernel_launch(void* const* d_in, const int* in_sizes, int n_in,
                              void* d_out, int out_size, void* d_ws, size_t ws_size,
                              hipStream_t stream) {
    const float* x   = (const float*)d_in[0];
    const float* Wk  = (const float*)d_in[1];
    const float* Wq  = (const float*)d_in[2];
    const float* Wv  = (const float*)d_in[3];
    const float* Wo  = (const float*)d_in[4];
    const float* bo  = (const float*)d_in[5];
    const float* W1  = (const float*)d_in[6];
    const float* b1  = (const float*)d_in[7];
    const float* W2  = (const float*)d_in[8];
    const float* b2  = (const float*)d_in[9];
    const float* g1  = (const float*)d_in[10];
    const float* be1 = (const float*)d_in[11];
    const float* g2  = (const float*)d_in[12];
    const float* be2 = (const float*)d_in[13];

    char* ws = (char*)d_ws;
    u16* hbuf = (u16*)(ws + 0);            // 25165824 B (h1, later h2)
    u16* qkv  = (u16*)(ws + 25165824);     // 75497472 B
    u16* ao   = (u16*)(ws + 100663296);    // 25165824 B
    u16* x1   = (u16*)(ws + 125829120);    // 25165824 B (bf16 now)
    u16* ubuf = (u16*)(ws + 25165824);     // 100663296 B (aliases qkv+ao, both dead)
    u16* wT   = (u16*)(ws + 150994944);    // 3538944 B of bf16 weights
    u16* wqkvT = wT;                  // [1152][384]: q 0-383, k 384-767, v 768-1151
    u16* woT   = wT + 442368;         // [384][384]
    u16* w1T   = woT + 147456;        // [1536][384]
    u16* w2T   = w1T + 589824;        // [384][1536]

    tcvt_all<<<6912, 256, 0, stream>>>(Wq, Wk, Wv, Wo, W1, W2, wT);

    // h1 = LN(x)
    ln_kernel<<<8192, 256, 0, stream>>>(x, g1, be1, hbuf);
    // qkv = h1 @ [Wq|Wk|Wv]
    gemm_kernel<0, 0, 0, 0, 1, 9><<<2304, 256, 0, stream>>>(
        hbuf, wqkvT, nullptr, nullptr, qkv, 32768, 1152, 384);
    // attention
    attn_kernel<<<dim3(2, 6, 128), 512, 0, stream>>>(qkv, ao);
    // x1 = x + ao @ Wo + bo   (bf16 out)
    gemm_kernel<1, 0, 1, 0, 1, 3><<<768, 256, 0, stream>>>(
        ao, woT, bo, x, x1, 32768, 384, 384);
    // h2 = LN(x1)
    ln_bf16_kernel<<<8192, 256, 0, stream>>>(x1, g2, be2, hbuf);
    // u = relu(h2 @ W1 + b1)
    gemm_kernel<1, 1, 0, 0, 1, 12><<<3072, 256, 0, stream>>>(
        hbuf, w1T, b1, nullptr, ubuf, 32768, 1536, 384);
    // out = x1 + u @ W2 + b2  (fp32 out, bf16 res)
    gemm_kernel<1, 0, 1, 1, 0, 3><<<768, 256, 0, stream>>>(
        ubuf, w2T, b2, x1, (float*)d_out, 32768, 384, 1536);
}

// Round 4
// 287.888 us; speedup vs baseline: 1.2376x; 1.0022x over previous
//
#include <hip/hip_runtime.h>

typedef unsigned short u16;
typedef short s16x8 __attribute__((ext_vector_type(8)));
typedef float f32x4 __attribute__((ext_vector_type(4)));

__device__ inline u16 f2bf(float f) {
    unsigned u = __float_as_uint(f);
    u += 0x7FFF + ((u >> 16) & 1);
    return (u16)(u >> 16);
}
__device__ inline float bf2f(u16 h) {
    return __uint_as_float((unsigned)h << 16);
}

__device__ inline f32x4 mfma16(s16x8 a, s16x8 b, f32x4 c) {
    return __builtin_amdgcn_mfma_f32_16x16x32_bf16(a, b, c, 0, 0, 0);
}

// async global->LDS, 16B per lane. LDS dest is wave-uniform base + lane*16.
__device__ __forceinline__ void gl16(const u16* g, u16* l) {
    __builtin_amdgcn_global_load_lds(
        (const __attribute__((address_space(1))) void*)g,
        (__attribute__((address_space(3))) void*)l, 16, 0, 0);
}

// All weight transposes fused in one launch. out = wT layout (bf16):
// [0,147456) Wq^T, [147456,294912) Wk^T, [294912,442368) Wv^T,
// [442368,589824) Wo^T, [589824,1179648) W1^T, [1179648,1769472) W2^T.
__global__ void tcvt_all(const float* __restrict__ Wq, const float* __restrict__ Wk,
                         const float* __restrict__ Wv, const float* __restrict__ Wo,
                         const float* __restrict__ W1, const float* __restrict__ W2,
                         u16* __restrict__ out) {
    int i = blockIdx.x * 256 + threadIdx.x;
    float val;
    if (i < 589824) {
        int q = i / 147456, j = i - q * 147456;
        const float* s = q == 0 ? Wq : q == 1 ? Wk : q == 2 ? Wv : Wo;
        int n = j / 384, k = j - n * 384;
        val = s[k * 384 + n];
    } else if (i < 1179648) {
        int j = i - 589824;
        int n = j / 384, k = j - n * 384;
        val = W1[(size_t)k * 1536 + n];
    } else {
        int j = i - 1179648;
        int n = j / 1536, k = j - n * 1536;
        val = W2[(size_t)k * 384 + n];
    }
    out[i] = f2bf(val);
}

// LayerNorm over rows of 384 fp32 -> bf16. One wave per row, 4 rows/block.
__global__ __launch_bounds__(256) void ln_kernel(const float* __restrict__ x,
                                                 const float* __restrict__ g,
                                                 const float* __restrict__ be,
                                                 u16* __restrict__ out) {
    int lane = threadIdx.x & 63;
    int w = threadIdx.x >> 6;
    int row = blockIdx.x * 4 + w;
    const float* xr = x + (size_t)row * 384;
    float v[6];
    float s = 0.f, sq = 0.f;
#pragma unroll
    for (int i = 0; i < 6; ++i) {
        v[i] = xr[i * 64 + lane];
        s += v[i];
        sq += v[i] * v[i];
    }
#pragma unroll
    for (int m = 1; m < 64; m <<= 1) {
        s += __shfl_xor(s, m);
        sq += __shfl_xor(sq, m);
    }
    float mu = s * (1.0f / 384.0f);
    float var = sq * (1.0f / 384.0f) - mu * mu;
    float rstd = rsqrtf(var + 1e-5f);
    u16* orow = out + (size_t)row * 384;
#pragma unroll
    for (int i = 0; i < 6; ++i) {
        int col = i * 64 + lane;
        orow[col] = f2bf((v[i] - mu) * rstd * g[col] + be[col]);
    }
}

// LayerNorm, bf16 input rows of 384 -> bf16. One wave/row, 48 active lanes x8.
__global__ __launch_bounds__(256) void ln_bf16_kernel(const u16* __restrict__ x,
                                                      const float* __restrict__ g,
                                                      const float* __restrict__ be,
                                                      u16* __restrict__ out) {
    int lane = threadIdx.x & 63;
    int w = threadIdx.x >> 6;
    int row = blockIdx.x * 4 + w;
    const u16* xr = x + (size_t)row * 384;
    bool act = lane < 48;
    float v[8];
    float s = 0.f, sq = 0.f;
    if (act) {
        s16x8 t = *(const s16x8*)&xr[lane * 8];
#pragma unroll
        for (int j = 0; j < 8; ++j) {
            v[j] = bf2f((u16)t[j]);
            s += v[j];
            sq += v[j] * v[j];
        }
    }
#pragma unroll
    for (int m = 1; m < 64; m <<= 1) {
        s += __shfl_xor(s, m);
        sq += __shfl_xor(sq, m);
    }
    float mu = s * (1.0f / 384.0f);
    float var = sq * (1.0f / 384.0f) - mu * mu;
    float rstd = rsqrtf(var + 1e-5f);
    if (act) {
        float4 g0 = *(const float4*)&g[lane * 8];
        float4 g1 = *(const float4*)&g[lane * 8 + 4];
        float4 b0 = *(const float4*)&be[lane * 8];
        float4 b1 = *(const float4*)&be[lane * 8 + 4];
        float gg[8] = {g0.x, g0.y, g0.z, g0.w, g1.x, g1.y, g1.z, g1.w};
        float bb[8] = {b0.x, b0.y, b0.z, b0.w, b1.x, b1.y, b1.z, b1.w};
        u16* orow = out + (size_t)row * 384 + lane * 8;
#pragma unroll
        for (int j = 0; j < 8; ++j)
            orow[j] = f2bf((v[j] - mu) * rstd * gg[j] + bb[j]);
    }
}

// bf16 GEMM, 3-buffer counted-vmcnt pipeline (T3+T4). A [M][K] rm, Bt [N][K] rm.
// Tile 128x128, BK=32, 4 waves x (64x64). global_load_lds width16, linear LDS
// write + XOR granule swizzle (pre-swizzled source addr, swizzled read addr).
// Per step t: vmcnt(4) [tile t drained, t+1 in flight]; barrier; stage t+2;
// ds_read+MFMA tile t. Load->use separation = 2 steps + 3 blocks/CU TLP.
template <int BIAS, int RELU, int RES, int RESBF, int OBF16, int NBX>
__global__ __launch_bounds__(256) void gemm_kernel(const u16* __restrict__ A,
                                                   const u16* __restrict__ Bt,
                                                   const float* __restrict__ bias,
                                                   const void* __restrict__ res,
                                                   void* __restrict__ out,
                                                   int M, int N, int K) {
    __shared__ u16 La[3][128 * 32];
    __shared__ u16 Lb[3][128 * 32];
    int tid = threadIdx.x;
    int lane = tid & 63, w = tid >> 6;
    int wm = w >> 1, wn = w & 1;
    int lr = lane & 15, lg = lane >> 4;

    // bijective XCD chunk swizzle (m204); consecutive wg share A-panels.
    int nwg = gridDim.x;
    int q = nwg >> 3, r = nwg & 7;
    int xcd = blockIdx.x & 7, lin = blockIdx.x >> 3;
    int wg = (xcd < r ? xcd * (q + 1) : r * (q + 1) + (xcd - r) * q) + lin;
    int bx = wg % NBX, by = wg / NBX;
    int m0 = by * 128, n0 = bx * 128;

    // staging: 4 lanes/row (16B each), rows w*32 + i*16 + (lane>>2).
    // reader expects physical granule p at row rr to hold global granule
    // p ^ ((rr>>1)&3); writer lane l sits at physical slot l&3.
    int gslot = ((lane & 3) ^ ((lane >> 3) & 3)) * 8;  // global col offset (elems)
    const u16* pa[2];
    const u16* pb[2];
#pragma unroll
    for (int i = 0; i < 2; ++i) {
        int rr = w * 32 + i * 16 + (lane >> 2);
        pa[i] = A + (size_t)(m0 + rr) * K + gslot;
        pb[i] = Bt + (size_t)(n0 + rr) * K + gslot;
    }

    f32x4 acc[4][4];
    f32x4 zero = {0.f, 0.f, 0.f, 0.f};
#pragma unroll
    for (int mt = 0; mt < 4; ++mt)
#pragma unroll
        for (int nt = 0; nt < 4; ++nt) acc[mt][nt] = zero;

    int sel = (lg ^ ((lr >> 1) & 3)) << 3;  // read-side swizzled granule (elems)
    int nt_steps = K >> 5;

    // stage tile t into buffer bsel
#define STAGE(t, bsel)                              \
    do {                                            \
        int kc = (t) << 5;                          \
        u16* la = La[bsel] + w * 1024;              \
        u16* lb = Lb[bsel] + w * 1024;              \
        gl16(pa[0] + kc, la);                       \
        gl16(pa[1] + kc, la + 512);                 \
        gl16(pb[0] + kc, lb);                       \
        gl16(pb[1] + kc, lb + 512);                 \
    } while (0)

    STAGE(0, 0);
    STAGE(1, 1);

    int cur = 0;   // buffer of tile t
    int nxt = 2;   // buffer for tile t+2
    for (int t = 0; t < nt_steps; ++t) {
        if (t < nt_steps - 1)
            asm volatile("s_waitcnt vmcnt(4)" ::: "memory");
        else
            asm volatile("s_waitcnt vmcnt(0)" ::: "memory");
        __builtin_amdgcn_s_barrier();
        asm volatile("" ::: "memory");
        if (t + 2 < nt_steps) STAGE(t + 2, nxt);
        const u16* lab = La[cur];
        const u16* lbb = Lb[cur];
        s16x8 af[4], bfr[4];
#pragma unroll
        for (int tt = 0; tt < 4; ++tt) {
            int mr = wm * 64 + tt * 16 + lr;
            int nr = wn * 64 + tt * 16 + lr;
            af[tt] = *(const s16x8*)&lab[mr * 32 + sel];
            bfr[tt] = *(const s16x8*)&lbb[nr * 32 + sel];
        }
#pragma unroll
        for (int mt = 0; mt < 4; ++mt)
#pragma unroll
            for (int nt = 0; nt < 4; ++nt)
                acc[mt][nt] = mfma16(af[mt], bfr[nt], acc[mt][nt]);
        cur = cur == 2 ? 0 : cur + 1;
        nxt = nxt == 2 ? 0 : nxt + 1;
    }
#undef STAGE

#pragma unroll
    for (int mt = 0; mt < 4; ++mt) {
#pragma unroll
        for (int nt = 0; nt < 4; ++nt) {
            int m_base = m0 + wm * 64 + mt * 16 + lg * 4;
            int n = n0 + wn * 64 + nt * 16 + lr;
            float bv = BIAS ? bias[n] : 0.0f;
#pragma unroll
            for (int r2 = 0; r2 < 4; ++r2) {
                size_t idx = (size_t)(m_base + r2) * N + n;
                float val = acc[mt][nt][r2] + bv;
                if (RES) {
                    if (RESBF)
                        val += bf2f(((const u16*)res)[idx]);
                    else
                        val += ((const float*)res)[idx];
                }
                if (RELU) val = fmaxf(val, 0.0f);
                if (OBF16)
                    ((u16*)out)[idx] = f2bf(val);
                else
                    ((float*)out)[idx] = val;
            }
        }
    }
}

// Causal attention for one (b, h, 128-q-row tile). qkv: [B*T][1152] bf16
// (cols: q 0-383, k 384-767, v 768-1151; within each, h*64+d).
// 8 waves x 16 q-rows. Full 256-col score row per wave in registers.
__global__ __launch_bounds__(512) void attn_kernel(const u16* __restrict__ qkv,
                                                   u16* __restrict__ aout) {
    __shared__ u16 Kl[256 * 72];   // K rows [t][d], pad 64->72
    __shared__ u16 Vt[64 * 264];   // V transposed [d][t], pad 256->264
    __shared__ u16 Pl[8 * 16 * 264];  // per-wave P [16][t], pad
    int qt = blockIdx.x, h = blockIdx.y, b = blockIdx.z;
    int tid = threadIdx.x, lane = tid & 63, w = tid >> 6;
    int lr = lane & 15, lg = lane >> 4;
    const u16* qb = qkv + (size_t)b * 256 * 1152;

#pragma unroll
    for (int i = 0; i < 4; ++i) {
        int c = tid + i * 512;
        int t = c >> 3, dch = c & 7;
        *(int4*)&Kl[t * 72 + dch * 8] =
            *(const int4*)(qb + (size_t)t * 1152 + 384 + h * 64 + dch * 8);
        union { int4 v; u16 u[8]; } vv;
        vv.v = *(const int4*)(qb + (size_t)t * 1152 + 768 + h * 64 + dch * 8);
#pragma unroll
        for (int j = 0; j < 8; ++j) Vt[(dch * 8 + j) * 264 + t] = vv.u[j];
    }

    int q0 = qt * 128;
    const u16* qrow = qb + (size_t)(q0 + w * 16 + lr) * 1152 + h * 64;
    s16x8 qf0 = *(const s16x8*)(qrow + lg * 8);
    s16x8 qf1 = *(const s16x8*)(qrow + 32 + lg * 8);

    __syncthreads();

    f32x4 zero = {0.f, 0.f, 0.f, 0.f};
    f32x4 s[16];
#pragma unroll
    for (int nt = 0; nt < 16; ++nt) s[nt] = zero;
#pragma unroll
    for (int nt = 0; nt < 16; ++nt) {
        s16x8 kf0 = *(const s16x8*)&Kl[(nt * 16 + lr) * 72 + lg * 8];
        s16x8 kf1 = *(const s16x8*)&Kl[(nt * 16 + lr) * 72 + 32 + lg * 8];
        s[nt] = mfma16(qf0, kf0, s[nt]);
        s[nt] = mfma16(qf1, kf1, s[nt]);
    }

    // scale + causal mask + row max (rows: lg*4+r, cols: nt*16+lr)
    int ib = q0 + w * 16 + lg * 4;
    float mx[4] = {-1e30f, -1e30f, -1e30f, -1e30f};
#pragma unroll
    for (int nt = 0; nt < 16; ++nt) {
        int jg = nt * 16 + lr;
#pragma unroll
        for (int r = 0; r < 4; ++r) {
            float val = s[nt][r] * 0.125f;
            val = (jg <= ib + r) ? val : -1e30f;
            s[nt][r] = val;
            mx[r] = fmaxf(mx[r], val);
        }
    }
#pragma unroll
    for (int r = 0; r < 4; ++r) {
        mx[r] = fmaxf(mx[r], __shfl_xor(mx[r], 1));
        mx[r] = fmaxf(mx[r], __shfl_xor(mx[r], 2));
        mx[r] = fmaxf(mx[r], __shfl_xor(mx[r], 4));
        mx[r] = fmaxf(mx[r], __shfl_xor(mx[r], 8));
    }
    float rs[4] = {0.f, 0.f, 0.f, 0.f};
#pragma unroll
    for (int nt = 0; nt < 16; ++nt) {
#pragma unroll
        for (int r = 0; r < 4; ++r) {
            float p = __expf(s[nt][r] - mx[r]);
            s[nt][r] = p;
            rs[r] += p;
        }
    }
#pragma unroll
    for (int r = 0; r < 4; ++r) {
        rs[r] += __shfl_xor(rs[r], 1);
        rs[r] += __shfl_xor(rs[r], 2);
        rs[r] += __shfl_xor(rs[r], 4);
        rs[r] += __shfl_xor(rs[r], 8);
    }
    // write unnormalized P (bf16) to LDS
    u16* Pw = &Pl[w * 16 * 264];
#pragma unroll
    for (int nt = 0; nt < 16; ++nt)
#pragma unroll
        for (int r = 0; r < 4; ++r)
            Pw[(lg * 4 + r) * 264 + nt * 16 + lr] = f2bf(s[nt][r]);

    __syncthreads();

    f32x4 o[4];
#pragma unroll
    for (int nt = 0; nt < 4; ++nt) o[nt] = zero;
#pragma unroll
    for (int kc = 0; kc < 8; ++kc) {
        s16x8 pf = *(const s16x8*)&Pw[lr * 264 + kc * 32 + lg * 8];
#pragma unroll
        for (int nt = 0; nt < 4; ++nt) {
            s16x8 vf = *(const s16x8*)&Vt[(nt * 16 + lr) * 264 + kc * 32 + lg * 8];
            o[nt] = mfma16(pf, vf, o[nt]);
        }
    }
    float inv[4];
#pragma unroll
    for (int r = 0; r < 4; ++r) inv[r] = 1.0f / rs[r];
    u16* ob = aout + (size_t)(b * 256 + q0 + w * 16) * 384 + h * 64;
#pragma unroll
    for (int nt = 0; nt < 4; ++nt)
#pragma unroll
        for (int r = 0; r < 4; ++r)
            ob[(size_t)(lg * 4 + r) * 384 + nt * 16 + lr] = f2bf(o[nt][r] * inv[r]);
}

extern "C" void kernel_launch(void* const* d_in, const int* in_sizes, int n_in,
                              void* d_out, int out_size, void* d_ws, size_t ws_size,
                              hipStream_t stream) {
    const float* x   = (const float*)d_in[0];
    const float* Wk  = (const float*)d_in[1];
    const float* Wq  = (const float*)d_in[2];
    const float* Wv  = (const float*)d_in[3];
    const float* Wo  = (const float*)d_in[4];
    const float* bo  = (const float*)d_in[5];
    const float* W1  = (const float*)d_in[6];
    const float* b1  = (const float*)d_in[7];
    const float* W2  = (const float*)d_in[8];
    const float* b2  = (const float*)d_in[9];
    const float* g1  = (const float*)d_in[10];
    const float* be1 = (const float*)d_in[11];
    const float* g2  = (const float*)d_in[12];
    const float* be2 = (const float*)d_in[13];

    char* ws = (char*)d_ws;
    u16* hbuf = (u16*)(ws + 0);            // 25165824 B (h1, later h2)
    u16* qkv  = (u16*)(ws + 25165824);     // 75497472 B
    u16* ao   = (u16*)(ws + 100663296);    // 25165824 B
    u16* x1   = (u16*)(ws + 125829120);    // 25165824 B (bf16)
    u16* ubuf = (u16*)(ws + 25165824);     // 100663296 B (aliases qkv+ao, both dead)
    u16* wT   = (u16*)(ws + 150994944);    // 3538944 B of bf16 weights
    u16* wqkvT = wT;                  // [1152][384]: q 0-383, k 384-767, v 768-1151
    u16* woT   = wT + 442368;         // [384][384]
    u16* w1T   = woT + 147456;        // [1536][384]
    u16* w2T   = w1T + 589824;        // [384][1536]

    tcvt_all<<<6912, 256, 0, stream>>>(Wq, Wk, Wv, Wo, W1, W2, wT);

    // h1 = LN(x)
    ln_kernel<<<8192, 256, 0, stream>>>(x, g1, be1, hbuf);
    // qkv = h1 @ [Wq|Wk|Wv]
    gemm_kernel<0, 0, 0, 0, 1, 9><<<2304, 256, 0, stream>>>(
        hbuf, wqkvT, nullptr, nullptr, qkv, 32768, 1152, 384);
    // attention
    attn_kernel<<<dim3(2, 6, 128), 512, 0, stream>>>(qkv, ao);
    // x1 = x + ao @ Wo + bo   (bf16 out)
    gemm_kernel<1, 0, 1, 0, 1, 3><<<768, 256, 0, stream>>>(
        ao, woT, bo, x, x1, 32768, 384, 384);
    // h2 = LN(x1)
    ln_bf16_kernel<<<8192, 256, 0, stream>>>(x1, g2, be2, hbuf);
    // u = relu(h2 @ W1 + b1)
    gemm_kernel<1, 1, 0, 0, 1, 12><<<3072, 256, 0, stream>>>(
        hbuf, w1T, b1, nullptr, ubuf, 32768, 1536, 384);
    // out = x1 + u @ W2 + b2  (fp32 out, bf16 res)
    gemm_kernel<1, 0, 1, 1, 0, 3><<<768, 256, 0, stream>>>(
        ubuf, w2T, b2, x1, (float*)d_out, 32768, 384, 1536);
}

// Round 5
// 262.644 us; speedup vs baseline: 1.3565x; 1.0961x over previous
//
#include <hip/hip_runtime.h>

typedef unsigned short u16;
typedef short s16x8 __attribute__((ext_vector_type(8)));
typedef float f32x4 __attribute__((ext_vector_type(4)));

__device__ inline u16 f2bf(float f) {
    unsigned u = __float_as_uint(f);
    u += 0x7FFF + ((u >> 16) & 1);
    return (u16)(u >> 16);
}
__device__ inline float bf2f(u16 h) {
    return __uint_as_float((unsigned)h << 16);
}

__device__ inline f32x4 mfma16(s16x8 a, s16x8 b, f32x4 c) {
    return __builtin_amdgcn_mfma_f32_16x16x32_bf16(a, b, c, 0, 0, 0);
}

// async global->LDS, 16B per lane. LDS dest is wave-uniform base + lane*16.
__device__ __forceinline__ void gl16(const u16* g, u16* l) {
    __builtin_amdgcn_global_load_lds(
        (const __attribute__((address_space(1))) void*)g,
        (__attribute__((address_space(3))) void*)l, 16, 0, 0);
}

// All weight transposes fused in one launch. out = wT layout (bf16):
// [0,147456) Wq^T, [147456,294912) Wk^T, [294912,442368) Wv^T,
// [442368,589824) Wo^T, [589824,1179648) W1^T, [1179648,1769472) W2^T.
__global__ void tcvt_all(const float* __restrict__ Wq, const float* __restrict__ Wk,
                         const float* __restrict__ Wv, const float* __restrict__ Wo,
                         const float* __restrict__ W1, const float* __restrict__ W2,
                         u16* __restrict__ out) {
    int i = blockIdx.x * 256 + threadIdx.x;
    float val;
    if (i < 589824) {
        int q = i / 147456, j = i - q * 147456;
        const float* s = q == 0 ? Wq : q == 1 ? Wk : q == 2 ? Wv : Wo;
        int n = j / 384, k = j - n * 384;
        val = s[k * 384 + n];
    } else if (i < 1179648) {
        int j = i - 589824;
        int n = j / 384, k = j - n * 384;
        val = W1[(size_t)k * 1536 + n];
    } else {
        int j = i - 1179648;
        int n = j / 1536, k = j - n * 1536;
        val = W2[(size_t)k * 384 + n];
    }
    out[i] = f2bf(val);
}

// LayerNorm over rows of 384 fp32 -> bf16. One wave per row, 4 rows/block.
__global__ __launch_bounds__(256) void ln_kernel(const float* __restrict__ x,
                                                 const float* __restrict__ g,
                                                 const float* __restrict__ be,
                                                 u16* __restrict__ out) {
    int lane = threadIdx.x & 63;
    int w = threadIdx.x >> 6;
    int row = blockIdx.x * 4 + w;
    const float* xr = x + (size_t)row * 384;
    float v[6];
    float s = 0.f, sq = 0.f;
#pragma unroll
    for (int i = 0; i < 6; ++i) {
        v[i] = xr[i * 64 + lane];
        s += v[i];
        sq += v[i] * v[i];
    }
#pragma unroll
    for (int m = 1; m < 64; m <<= 1) {
        s += __shfl_xor(s, m);
        sq += __shfl_xor(sq, m);
    }
    float mu = s * (1.0f / 384.0f);
    float var = sq * (1.0f / 384.0f) - mu * mu;
    float rstd = rsqrtf(var + 1e-5f);
    u16* orow = out + (size_t)row * 384;
#pragma unroll
    for (int i = 0; i < 6; ++i) {
        int col = i * 64 + lane;
        orow[col] = f2bf((v[i] - mu) * rstd * g[col] + be[col]);
    }
}

// LayerNorm, bf16 input rows of 384 -> bf16. One wave/row, 48 active lanes x8.
__global__ __launch_bounds__(256) void ln_bf16_kernel(const u16* __restrict__ x,
                                                      const float* __restrict__ g,
                                                      const float* __restrict__ be,
                                                      u16* __restrict__ out) {
    int lane = threadIdx.x & 63;
    int w = threadIdx.x >> 6;
    int row = blockIdx.x * 4 + w;
    const u16* xr = x + (size_t)row * 384;
    bool act = lane < 48;
    float v[8];
    float s = 0.f, sq = 0.f;
    if (act) {
        s16x8 t = *(const s16x8*)&xr[lane * 8];
#pragma unroll
        for (int j = 0; j < 8; ++j) {
            v[j] = bf2f((u16)t[j]);
            s += v[j];
            sq += v[j] * v[j];
        }
    }
#pragma unroll
    for (int m = 1; m < 64; m <<= 1) {
        s += __shfl_xor(s, m);
        sq += __shfl_xor(sq, m);
    }
    float mu = s * (1.0f / 384.0f);
    float var = sq * (1.0f / 384.0f) - mu * mu;
    float rstd = rsqrtf(var + 1e-5f);
    if (act) {
        float4 g0 = *(const float4*)&g[lane * 8];
        float4 g1 = *(const float4*)&g[lane * 8 + 4];
        float4 b0 = *(const float4*)&be[lane * 8];
        float4 b1 = *(const float4*)&be[lane * 8 + 4];
        float gg[8] = {g0.x, g0.y, g0.z, g0.w, g1.x, g1.y, g1.z, g1.w};
        float bb[8] = {b0.x, b0.y, b0.z, b0.w, b1.x, b1.y, b1.z, b1.w};
        u16* orow = out + (size_t)row * 384 + lane * 8;
#pragma unroll
        for (int j = 0; j < 8; ++j)
            orow[j] = f2bf((v[j] - mu) * rstd * gg[j] + bb[j]);
    }
}

// bf16 GEMM, 256x192 tile, BK=64, 8 waves (each 64x96 = 4x6 frags).
// A [M][K] rm, Bt [N][K] rm. global_load_lds w16, linear LDS write +
// 8-granule XOR swizzle (pre-swizzled source + swizzled read, rule #21).
// 2-buffer, 1-step prefetch: step wall (~20 ds_read_b128 + 48 MFMA per wave,
// 2 waves/SIMD) covers next tile's load latency. LDS 112 KB -> 1 block/CU.
template <int BIAS, int RELU, int RES, int RESBF, int OBF16, int NBN>
__global__ __launch_bounds__(512, 2) void gemm_kernel(const u16* __restrict__ A,
                                                      const u16* __restrict__ Bt,
                                                      const float* __restrict__ bias,
                                                      const void* __restrict__ res,
                                                      void* __restrict__ out,
                                                      int M, int N, int K) {
    __shared__ u16 La[2][256 * 64];
    __shared__ u16 Lb[2][192 * 64];
    int tid = threadIdx.x;
    int lane = tid & 63, w = tid >> 6;   // 8 waves
    int wm = w >> 1, wn = w & 1;         // 4 x 2 wave grid
    int lr = lane & 15, lg = lane >> 4;

    // bijective XCD chunk swizzle (m204); NBN column-siblings of an A-panel
    // are consecutive wg -> same XCD -> A-panel L2 reuse.
    int nwg = gridDim.x;
    int q = nwg >> 3, r = nwg & 7;
    int xcd = blockIdx.x & 7, lin = blockIdx.x >> 3;
    int wg = (xcd < r ? xcd * (q + 1) : r * (q + 1) + (xcd - r) * q) + lin;
    int bx = wg % NBN, by = wg / NBN;
    int m0 = by * 256, n0 = bx * 192;

    // staging: rows are 64 elems (128 B), 8 lanes/row, 8 rows per gl16.
    // physical granule p of row rr holds global granule p ^ (rr&7).
    int rsub = lane >> 3;                      // row within 8
    int gslot = ((lane & 7) ^ rsub) * 8;       // pre-swizzled source granule
    const u16* pa[4];
    const u16* pb[3];
#pragma unroll
    for (int i = 0; i < 4; ++i)
        pa[i] = A + (size_t)(m0 + w * 32 + i * 8 + rsub) * K + gslot;
#pragma unroll
    for (int i = 0; i < 3; ++i)
        pb[i] = Bt + (size_t)(n0 + w * 24 + i * 8 + rsub) * K + gslot;

    f32x4 acc[4][6];
    f32x4 zero = {0.f, 0.f, 0.f, 0.f};
#pragma unroll
    for (int mt = 0; mt < 4; ++mt)
#pragma unroll
        for (int nt = 0; nt < 6; ++nt) acc[mt][nt] = zero;

    // read-side swizzled granule offsets (elems) for kk=0,1
    int s0 = (lg ^ (lr & 7)) * 8;
    int s1 = ((4 + lg) ^ (lr & 7)) * 8;
    int nt_steps = K >> 6;

#define STAGE(t, bsel)                                        \
    do {                                                      \
        int kc = (t) << 6;                                    \
        _Pragma("unroll")                                     \
        for (int i = 0; i < 4; ++i)                           \
            gl16(pa[i] + kc, &La[bsel][(w * 32 + i * 8) * 64]); \
        _Pragma("unroll")                                     \
        for (int i = 0; i < 3; ++i)                           \
            gl16(pb[i] + kc, &Lb[bsel][(w * 24 + i * 8) * 64]); \
    } while (0)

    STAGE(0, 0);

    for (int t = 0; t < nt_steps; ++t) {
        asm volatile("s_waitcnt vmcnt(0)" ::: "memory");
        __builtin_amdgcn_s_barrier();
        asm volatile("" ::: "memory");
        if (t + 1 < nt_steps) STAGE(t + 1, (t + 1) & 1);
        const u16* lab = La[t & 1];
        const u16* lbb = Lb[t & 1];
        s16x8 af[2][4], bfr[2][6];
#pragma unroll
        for (int mt = 0; mt < 4; ++mt) {
            int mr = wm * 64 + mt * 16 + lr;
            af[0][mt] = *(const s16x8*)&lab[mr * 64 + s0];
            af[1][mt] = *(const s16x8*)&lab[mr * 64 + s1];
        }
#pragma unroll
        for (int nt = 0; nt < 6; ++nt) {
            int nr = wn * 96 + nt * 16 + lr;
            bfr[0][nt] = *(const s16x8*)&lbb[nr * 64 + s0];
            bfr[1][nt] = *(const s16x8*)&lbb[nr * 64 + s1];
        }
#pragma unroll
        for (int kk = 0; kk < 2; ++kk)
#pragma unroll
            for (int mt = 0; mt < 4; ++mt)
#pragma unroll
                for (int nt = 0; nt < 6; ++nt)
                    acc[mt][nt] = mfma16(af[kk][mt], bfr[kk][nt], acc[mt][nt]);
    }
#undef STAGE

#pragma unroll
    for (int mt = 0; mt < 4; ++mt) {
#pragma unroll
        for (int nt = 0; nt < 6; ++nt) {
            int m_base = m0 + wm * 64 + mt * 16 + lg * 4;
            int n = n0 + wn * 96 + nt * 16 + lr;
            float bv = BIAS ? bias[n] : 0.0f;
#pragma unroll
            for (int r2 = 0; r2 < 4; ++r2) {
                size_t idx = (size_t)(m_base + r2) * N + n;
                float val = acc[mt][nt][r2] + bv;
                if (RES) {
                    if (RESBF)
                        val += bf2f(((const u16*)res)[idx]);
                    else
                        val += ((const float*)res)[idx];
                }
                if (RELU) val = fmaxf(val, 0.0f);
                if (OBF16)
                    ((u16*)out)[idx] = f2bf(val);
                else
                    ((float*)out)[idx] = val;
            }
        }
    }
}

// Causal attention for one (b, h, 128-q-row tile). qkv: [B*T][1152] bf16
// (cols: q 0-383, k 384-767, v 768-1151; within each, h*64+d).
// 8 waves x 16 q-rows. Full 256-col score row per wave in registers.
__global__ __launch_bounds__(512) void attn_kernel(const u16* __restrict__ qkv,
                                                   u16* __restrict__ aout) {
    __shared__ u16 Kl[256 * 72];   // K rows [t][d], pad 64->72
    __shared__ u16 Vt[64 * 264];   // V transposed [d][t], pad 256->264
    __shared__ u16 Pl[8 * 16 * 264];  // per-wave P [16][t], pad
    int qt = blockIdx.x, h = blockIdx.y, b = blockIdx.z;
    int tid = threadIdx.x, lane = tid & 63, w = tid >> 6;
    int lr = lane & 15, lg = lane >> 4;
    const u16* qb = qkv + (size_t)b * 256 * 1152;

#pragma unroll
    for (int i = 0; i < 4; ++i) {
        int c = tid + i * 512;
        int t = c >> 3, dch = c & 7;
        *(int4*)&Kl[t * 72 + dch * 8] =
            *(const int4*)(qb + (size_t)t * 1152 + 384 + h * 64 + dch * 8);
        union { int4 v; u16 u[8]; } vv;
        vv.v = *(const int4*)(qb + (size_t)t * 1152 + 768 + h * 64 + dch * 8);
#pragma unroll
        for (int j = 0; j < 8; ++j) Vt[(dch * 8 + j) * 264 + t] = vv.u[j];
    }

    int q0 = qt * 128;
    const u16* qrow = qb + (size_t)(q0 + w * 16 + lr) * 1152 + h * 64;
    s16x8 qf0 = *(const s16x8*)(qrow + lg * 8);
    s16x8 qf1 = *(const s16x8*)(qrow + 32 + lg * 8);

    __syncthreads();

    f32x4 zero = {0.f, 0.f, 0.f, 0.f};
    f32x4 s[16];
#pragma unroll
    for (int nt = 0; nt < 16; ++nt) s[nt] = zero;
#pragma unroll
    for (int nt = 0; nt < 16; ++nt) {
        s16x8 kf0 = *(const s16x8*)&Kl[(nt * 16 + lr) * 72 + lg * 8];
        s16x8 kf1 = *(const s16x8*)&Kl[(nt * 16 + lr) * 72 + 32 + lg * 8];
        s[nt] = mfma16(qf0, kf0, s[nt]);
        s[nt] = mfma16(qf1, kf1, s[nt]);
    }

    // scale + causal mask + row max (rows: lg*4+r, cols: nt*16+lr)
    int ib = q0 + w * 16 + lg * 4;
    float mx[4] = {-1e30f, -1e30f, -1e30f, -1e30f};
#pragma unroll
    for (int nt = 0; nt < 16; ++nt) {
        int jg = nt * 16 + lr;
#pragma unroll
        for (int r = 0; r < 4; ++r) {
            float val = s[nt][r] * 0.125f;
            val = (jg <= ib + r) ? val : -1e30f;
            s[nt][r] = val;
            mx[r] = fmaxf(mx[r], val);
        }
    }
#pragma unroll
    for (int r = 0; r < 4; ++r) {
        mx[r] = fmaxf(mx[r], __shfl_xor(mx[r], 1));
        mx[r] = fmaxf(mx[r], __shfl_xor(mx[r], 2));
        mx[r] = fmaxf(mx[r], __shfl_xor(mx[r], 4));
        mx[r] = fmaxf(mx[r], __shfl_xor(mx[r], 8));
    }
    float rs[4] = {0.f, 0.f, 0.f, 0.f};
#pragma unroll
    for (int nt = 0; nt < 16; ++nt) {
#pragma unroll
        for (int r = 0; r < 4; ++r) {
            float p = __expf(s[nt][r] - mx[r]);
            s[nt][r] = p;
            rs[r] += p;
        }
    }
#pragma unroll
    for (int r = 0; r < 4; ++r) {
        rs[r] += __shfl_xor(rs[r], 1);
        rs[r] += __shfl_xor(rs[r], 2);
        rs[r] += __shfl_xor(rs[r], 4);
        rs[r] += __shfl_xor(rs[r], 8);
    }
    // write unnormalized P (bf16) to LDS
    u16* Pw = &Pl[w * 16 * 264];
#pragma unroll
    for (int nt = 0; nt < 16; ++nt)
#pragma unroll
        for (int r = 0; r < 4; ++r)
            Pw[(lg * 4 + r) * 264 + nt * 16 + lr] = f2bf(s[nt][r]);

    __syncthreads();

    f32x4 o[4];
#pragma unroll
    for (int nt = 0; nt < 4; ++nt) o[nt] = zero;
#pragma unroll
    for (int kc = 0; kc < 8; ++kc) {
        s16x8 pf = *(const s16x8*)&Pw[lr * 264 + kc * 32 + lg * 8];
#pragma unroll
        for (int nt = 0; nt < 4; ++nt) {
            s16x8 vf = *(const s16x8*)&Vt[(nt * 16 + lr) * 264 + kc * 32 + lg * 8];
            o[nt] = mfma16(pf, vf, o[nt]);
        }
    }
    float inv[4];
#pragma unroll
    for (int r = 0; r < 4; ++r) inv[r] = 1.0f / rs[r];
    u16* ob = aout + (size_t)(b * 256 + q0 + w * 16) * 384 + h * 64;
#pragma unroll
    for (int nt = 0; nt < 4; ++nt)
#pragma unroll
        for (int r = 0; r < 4; ++r)
            ob[(size_t)(lg * 4 + r) * 384 + nt * 16 + lr] = f2bf(o[nt][r] * inv[r]);
}

extern "C" void kernel_launch(void* const* d_in, const int* in_sizes, int n_in,
                              void* d_out, int out_size, void* d_ws, size_t ws_size,
                              hipStream_t stream) {
    const float* x   = (const float*)d_in[0];
    const float* Wk  = (const float*)d_in[1];
    const float* Wq  = (const float*)d_in[2];
    const float* Wv  = (const float*)d_in[3];
    const float* Wo  = (const float*)d_in[4];
    const float* bo  = (const float*)d_in[5];
    const float* W1  = (const float*)d_in[6];
    const float* b1  = (const float*)d_in[7];
    const float* W2  = (const float*)d_in[8];
    const float* b2  = (const float*)d_in[9];
    const float* g1  = (const float*)d_in[10];
    const float* be1 = (const float*)d_in[11];
    const float* g2  = (const float*)d_in[12];
    const float* be2 = (const float*)d_in[13];

    char* ws = (char*)d_ws;
    u16* hbuf = (u16*)(ws + 0);            // 25165824 B (h1, later h2)
    u16* qkv  = (u16*)(ws + 25165824);     // 75497472 B
    u16* ao   = (u16*)(ws + 100663296);    // 25165824 B
    u16* x1   = (u16*)(ws + 125829120);    // 25165824 B (bf16)
    u16* ubuf = (u16*)(ws + 25165824);     // 100663296 B (aliases qkv+ao, both dead)
    u16* wT   = (u16*)(ws + 150994944);    // 3538944 B of bf16 weights
    u16* wqkvT = wT;                  // [1152][384]: q 0-383, k 384-767, v 768-1151
    u16* woT   = wT + 442368;         // [384][384]
    u16* w1T   = woT + 147456;        // [1536][384]
    u16* w2T   = w1T + 589824;        // [384][1536]

    tcvt_all<<<6912, 256, 0, stream>>>(Wq, Wk, Wv, Wo, W1, W2, wT);

    // h1 = LN(x)
    ln_kernel<<<8192, 256, 0, stream>>>(x, g1, be1, hbuf);
    // qkv = h1 @ [Wq|Wk|Wv]
    gemm_kernel<0, 0, 0, 0, 1, 6><<<768, 512, 0, stream>>>(
        hbuf, wqkvT, nullptr, nullptr, qkv, 32768, 1152, 384);
    // attention
    attn_kernel<<<dim3(2, 6, 128), 512, 0, stream>>>(qkv, ao);
    // x1 = x + ao @ Wo + bo   (bf16 out)
    gemm_kernel<1, 0, 1, 0, 1, 2><<<256, 512, 0, stream>>>(
        ao, woT, bo, x, x1, 32768, 384, 384);
    // h2 = LN(x1)
    ln_bf16_kernel<<<8192, 256, 0, stream>>>(x1, g2, be2, hbuf);
    // u = relu(h2 @ W1 + b1)
    gemm_kernel<1, 1, 0, 0, 1, 8><<<1024, 512, 0, stream>>>(
        hbuf, w1T, b1, nullptr, ubuf, 32768, 1536, 384);
    // out = x1 + u @ W2 + b2  (fp32 out, bf16 res)
    gemm_kernel<1, 0, 1, 1, 0, 2><<<256, 512, 0, stream>>>(
        ubuf, w2T, b2, x1, (float*)d_out, 32768, 384, 1536);
}